// Round 2
// baseline (1026.872 us; speedup 1.0000x reference)
//
#include <hip/hip_runtime.h>
#include <math.h>

#define TPB 256
#define LW  1000

// ---- LDS layout (float offsets) ----
// Union region (phase1 staging vs phase2 cwp+f2 tile)
#define OFF_WFE   0        // 1200  wf reflect-extended (halo 100)
#define OFF_CUME  1200     // 1200  cumsum reflect-extended
#define OFF_DSE   2400     // 1200  div_x_smd reflect-extended
#define OFF_D1    3600     // 1000  9-tap derivative (zero pad)
#define OFF_SCAND 4600     // 512 floats = 256 doubles (scan partials)
#define OFF_CWP   0        // 1560 = 15*104  combined final-conv weights (shifted +2, zero padded)
#define OFF_F2T   1560     // 6600 = 15*440  features2 tile for current chunk
#define UNION_SZ  8160
#define OFF_F1E   8160     // 3060 = 3*1020 features1_norm, reflect-extended (halo 10)
#define OFF_OUTB  11220    // 1000 pre-softmax buffer
#define OFF_WS    12220    // 1080 = 15*3*24 w_sub padded rows
#define OFF_PART  13300    // 672 = 2*336 final-conv partials
#define OFF_RED   13972    // 4 reduction scratch
#define SMEM_F    13976    // 55,904 bytes

__device__ __forceinline__ float4 ld4(const float* p) { return *(const float4*)p; }

__device__ __forceinline__ float blk_red_max(float v, float* red) {
  #pragma unroll
  for (int o = 32; o > 0; o >>= 1) v = fmaxf(v, __shfl_xor(v, o, 64));
  const int w = threadIdx.x >> 6;
  if ((threadIdx.x & 63) == 0) red[w] = v;
  __syncthreads();
  float r = fmaxf(fmaxf(red[0], red[1]), fmaxf(red[2], red[3]));
  __syncthreads();
  return r;
}

__device__ __forceinline__ float blk_red_sum(float v, float* red) {
  #pragma unroll
  for (int o = 32; o > 0; o >>= 1) v += __shfl_xor(v, o, 64);
  const int w = threadIdx.x >> 6;
  if ((threadIdx.x & 63) == 0) red[w] = v;
  __syncthreads();
  float r = red[0] + red[1] + red[2] + red[3];
  __syncthreads();
  return r;
}

__device__ __forceinline__ int refl(int j) {
  return j < 0 ? -j : (j >= LW ? 2 * LW - 2 - j : j);
}

extern "C" __global__ void __launch_bounds__(TPB, 2)
spot_kernel(const float* __restrict__ wf_g,  const float* __restrict__ mask_g,
            const float* __restrict__ spe_g, const float* __restrict__ wca_g,
            const float* __restrict__ wx_g,  const float* __restrict__ wdv_g,
            const float* __restrict__ wrl_g, const float* __restrict__ wsub_g,
            const float* __restrict__ wcb_g, const float* __restrict__ wp_g,
            float* __restrict__ out_g)
{
  __shared__ __align__(16) float sm[SMEM_F];
  const int tid = threadIdx.x;
  const int b = blockIdx.x;
  const float* wf = wf_g + (size_t)b * LW;
  float* red = sm + OFF_RED;

  // ---------------- phase 0: staging, maxima, scan partials ----------------
  float hmx = -INFINITY;
  for (int i = tid; i < 1200; i += TPB) sm[OFF_WFE + i] = wf[refl(i - 100)];
  for (int t = tid; t < LW; t += TPB) hmx = fmaxf(hmx, wf[t]);
  float smx = -INFINITY;
  for (int t = tid; t < LW; t += TPB) smx = fmaxf(smx, spe_g[t]);
  for (int i = tid; i < 1080; i += TPB) {           // w_sub rows padded 21 -> 24
    int row = i / 24, k = i % 24;
    sm[OFF_WS + i] = (k < 21) ? wsub_g[row * 21 + k] : 0.f;
  }
  double* scand = (double*)(sm + OFF_SCAND);
  double l0 = 0, l1 = 0, l2 = 0, l3 = 0;
  if (tid < 250) {
    l0 = (double)wf[4 * tid + 0];
    l1 = l0 + (double)wf[4 * tid + 1];
    l2 = l1 + (double)wf[4 * tid + 2];
    l3 = l2 + (double)wf[4 * tid + 3];
  }
  scand[tid] = l3;

  hmx = blk_red_max(hmx, red);   // barriers inside also publish wfe/ws/scand
  smx = blk_red_max(smx, red);

  // per-sample 3-way mixing weights W
  const float h = hmx / smx;
  float a0 = -fmaxf(h - wp_g[0], 0.f);
  float a1 = -fmaxf(h - wp_g[1], 0.f);
  float a2 = -fmaxf(h - wp_g[2], 0.f);
  float am = fmaxf(a0, fmaxf(a1, a2));
  float e0 = expf(a0 - am), e1 = expf(a1 - am), e2 = expf(a2 - am);
  float es = e0 + e1 + e2;
  float Wv[3] = { e0 / es, e1 / es, e2 / es };
  float swca = 0.f;
  for (int k = 0; k < 121; ++k) swca += wca_g[k];   // uniform scalar loads

  // ---------------- cumsum: fp64 block scan ----------------
  if (tid < 64) {
    double s0 = scand[4 * tid], s1 = scand[4 * tid + 1];
    double s2 = scand[4 * tid + 2], s3 = scand[4 * tid + 3];
    double tot = s0 + s1 + s2 + s3;
    double inc = tot;
    #pragma unroll
    for (int o = 1; o < 64; o <<= 1) {
      double n = __shfl_up(inc, o, 64);
      if ((tid & 63) >= o) inc += n;
    }
    double ex = inc - tot;
    scand[4 * tid]     = ex;
    scand[4 * tid + 1] = ex + s0;
    scand[4 * tid + 2] = ex + s0 + s1;
    scand[4 * tid + 3] = ex + s0 + s1 + s2;
  }
  __syncthreads();
  if (tid < 250) {
    double base = scand[tid];
    sm[OFF_CUME + 100 + 4 * tid + 0] = (float)(base + l0);
    sm[OFF_CUME + 100 + 4 * tid + 1] = (float)(base + l1);
    sm[OFF_CUME + 100 + 4 * tid + 2] = (float)(base + l2);
    sm[OFF_CUME + 100 + 4 * tid + 3] = (float)(base + l3);
  }
  // d1: 9-tap derivative, zero padded (uses wfe core)
  const float dker[9] = {1.f/280.f, -4.f/105.f, 0.2f, -0.8f, 0.f, 0.8f, -0.2f, 4.f/105.f, -1.f/280.f};
  for (int t = tid; t < LW; t += TPB) {
    float a = 0.f;
    #pragma unroll
    for (int k = 0; k < 9; ++k) {
      if (k == 4) continue;
      int j = t + k - 4;
      float x = (j >= 0 && j < LW) ? sm[OFF_WFE + 100 + j] : 0.f;
      a = fmaf(dker[k], x, a);
    }
    sm[OFF_D1 + t] = a;
  }
  __syncthreads();
  // cum halos + dse core (51-tap running mean of d1, zero padded)
  for (int i = tid; i < 100; i += TPB) {
    sm[OFF_CUME + i]        = sm[OFF_CUME + 200 - i];
    sm[OFF_CUME + 1100 + i] = sm[OFF_CUME + 1098 - i];
  }
  for (int t = tid; t < LW; t += TPB) {
    int lo = t - 25 < 0 ? 0 : t - 25;
    int hi = t + 25 >= LW ? LW - 1 : t + 25;
    float a = 0.f;
    for (int j = lo; j <= hi; ++j) a += sm[OFF_D1 + j];
    sm[OFF_DSE + 100 + t] = a * (1.f / 51.f);
  }
  __syncthreads();
  for (int i = tid; i < 100; i += TPB) {
    sm[OFF_DSE + i]        = sm[OFF_DSE + 200 - i];
    sm[OFF_DSE + 1100 + i] = sm[OFF_DSE + 1098 - i];
  }
  __syncthreads();

  // ---------------- fused 121/101-tap reflect convs -> features1 ----------------
  float lsC = 0.f, lsX = 0.f, lsD = 0.f;
  if (tid < 250) {
    const int t0 = 4 * tid;
    const float* ce = sm + OFF_CUME + t0;
    const float* we = sm + OFF_WFE + t0;
    const float* de = sm + OFF_DSE + t0;
    float cw_[8], ww_[8], dw_[8];
    *(float4*)cw_ = ld4(ce); *(float4*)(cw_ + 4) = ld4(ce + 4);
    *(float4*)ww_ = ld4(we); *(float4*)(ww_ + 4) = ld4(we + 4);
    *(float4*)dw_ = ld4(de); *(float4*)(dw_ + 4) = ld4(de + 4);
    float aC[4] = {0,0,0,0}, aB[4] = {0,0,0,0}, aX[4] = {0,0,0,0}, aD[4] = {0,0,0,0};
    for (int g = 0; g < 120; g += 4) {
      #pragma unroll
      for (int kk = 0; kk < 4; ++kk) {
        const int k = g + kk;
        const float wa = wca_g[k], wxk = wx_g[k], wdk = wdv_g[k];
        #pragma unroll
        for (int j = 0; j < 4; ++j) {
          aC[j] = fmaf(wa,  cw_[kk + j], aC[j]);
          aX[j] = fmaf(wxk, ww_[kk + j], aX[j]);
          aD[j] = fmaf(wdk, dw_[kk + j], aD[j]);
        }
        if (k <= 100) {
          const float wr = wrl_g[k];
          #pragma unroll
          for (int j = 0; j < 4; ++j) aB[j] = fmaf(wr, cw_[kk + j], aB[j]);
        }
      }
      #pragma unroll
      for (int j = 0; j < 4; ++j) { cw_[j] = cw_[j+4]; ww_[j] = ww_[j+4]; dw_[j] = dw_[j+4]; }
      *(float4*)(cw_ + 4) = ld4(ce + g + 8);
      *(float4*)(ww_ + 4) = ld4(we + g + 8);
      *(float4*)(dw_ + 4) = ld4(de + g + 8);
    }
    { // tail tap k=120
      const float wa = wca_g[120], wxk = wx_g[120], wdk = wdv_g[120];
      #pragma unroll
      for (int j = 0; j < 4; ++j) {
        aC[j] = fmaf(wa,  cw_[j], aC[j]);
        aX[j] = fmaf(wxk, ww_[j], aX[j]);
        aD[j] = fmaf(wdk, dw_[j], aD[j]);
      }
    }
    #pragma unroll
    for (int j = 0; j < 4; ++j) {
      float fc = fmaxf(fmaf(-aB[j], swca, aC[j]), 0.f);
      float fx = fmaxf(aX[j], 0.f);
      float fd = fmaxf(aD[j], 0.f);
      sm[OFF_F1E +        10 + t0 + j] = fc;
      sm[OFF_F1E + 1020 + 10 + t0 + j] = fx;
      sm[OFF_F1E + 2040 + 10 + t0 + j] = fd;
      lsC += fc; lsX += fx; lsD += fd;
    }
  }
  const float SC = blk_red_sum(lsC, red) + 1e-10f;
  const float SX = blk_red_sum(lsX, red) + 1e-10f;
  const float SD = blk_red_sum(lsD, red) + 1e-10f;
  {
    const float iC = 1.f / SC, iX = 1.f / SX, iD = 1.f / SD;
    for (int t = tid; t < LW; t += TPB) {
      sm[OFF_F1E +        10 + t] *= iC;
      sm[OFF_F1E + 1020 + 10 + t] *= iX;
      sm[OFF_F1E + 2040 + 10 + t] *= iD;
    }
  }
  __syncthreads();
  // f1e reflect halos (10) + combined final-conv weights cwp (union region now free)
  for (int i = tid; i < 30; i += TPB) {
    int c = i / 10, j = i % 10;
    sm[OFF_F1E + c * 1020 + j]        = sm[OFF_F1E + c * 1020 + 20 - j];
    sm[OFF_F1E + c * 1020 + 1010 + j] = sm[OFF_F1E + c * 1020 + 1008 - j];
  }
  for (int i = tid; i < 1560; i += TPB) {
    int ch = i / 104, kk = i % 104;
    int k = kk - 2;
    float v = 0.f;
    if (k >= 0 && k <= 100) v = Wv[ch % 3] * wcb_g[(ch / 3) * 303 + k * 3 + (ch % 3)];
    sm[OFF_CWP + i] = v;
  }
  __syncthreads();

  // ---------------- chunked: w_sub conv -> f2 tile, then 101-tap combine ----------------
  for (int c = 0; c < 3; ++c) {
    const int t0c = 336 * c;
    const int CH = (c == 2) ? 328 : 336;
    const int NB = CH >> 2;
    // A: features2 tile (15 x 440), u = t0c-52+iu, zero outside [0,1000)
    for (int task = tid; task < 1650; task += TPB) {
      const int ch = task / 110;
      const int ub = task - ch * 110;
      const int ubase = t0c - 52 + 4 * ub;
      float r0 = 0, r1 = 0, r2 = 0, r3 = 0;
      if (ubase >= 0 && ubase < LW) {
        float acc[4] = {0,0,0,0};
        #pragma unroll
        for (int cin = 0; cin < 3; ++cin) {
          const float* xr = sm + OFF_F1E + cin * 1020 + ubase;
          const float* wr = sm + OFF_WS + (ch * 3 + cin) * 24;
          float xw[8];
          *(float4*)xw = ld4(xr); *(float4*)(xw + 4) = ld4(xr + 4);
          #pragma unroll
          for (int g = 0; g < 20; g += 4) {
            float4 w4 = ld4(wr + g);
            float wv[4] = {w4.x, w4.y, w4.z, w4.w};
            #pragma unroll
            for (int kk = 0; kk < 4; ++kk)
              #pragma unroll
              for (int j = 0; j < 4; ++j) acc[j] = fmaf(wv[kk], xw[kk + j], acc[j]);
            if (g < 16) {
              #pragma unroll
              for (int j = 0; j < 4; ++j) xw[j] = xw[j + 4];
              *(float4*)(xw + 4) = ld4(xr + g + 8);
            }
          }
          const float w20 = wr[20];
          #pragma unroll
          for (int j = 0; j < 4; ++j) acc[j] = fmaf(w20, xw[4 + j], acc[j]);
        }
        r0 = acc[0]; r1 = acc[1]; r2 = acc[2]; r3 = acc[3];
      }
      float4 st = {r0, r1, r2, r3};
      *(float4*)(sm + OFF_F2T + ch * 440 + 4 * ub) = st;
    }
    __syncthreads();
    // B: final 101-tap combine; 3 ch-groups x NB t-blocks
    {
      const int nb3 = 3 * NB;
      if (tid < nb3) {
        const int grp = tid / NB;
        const int tb  = tid - grp * NB;
        float acc[4] = {0,0,0,0};
        for (int ch = grp * 5; ch < grp * 5 + 5; ++ch) {
          const float* xr = sm + OFF_F2T + ch * 440 + 4 * tb;
          const float* wr = sm + OFF_CWP + ch * 104;
          float xw[8];
          *(float4*)xw = ld4(xr); *(float4*)(xw + 4) = ld4(xr + 4);
          for (int kk = 0; kk <= 100; kk += 4) {
            float4 w4 = ld4(wr + kk);
            float wv[4] = {w4.x, w4.y, w4.z, w4.w};
            #pragma unroll
            for (int t = 0; t < 4; ++t)
              #pragma unroll
              for (int j = 0; j < 4; ++j) acc[j] = fmaf(wv[t], xw[t + j], acc[j]);
            if (kk < 100) {
              #pragma unroll
              for (int j = 0; j < 4; ++j) xw[j] = xw[j + 4];
              *(float4*)(xw + 4) = ld4(xr + kk + 8);
            }
          }
        }
        float4 st = {acc[0], acc[1], acc[2], acc[3]};
        if (grp == 0)      *(float4*)(sm + OFF_OUTB + t0c + 4 * tb) = st;
        else if (grp == 1) *(float4*)(sm + OFF_PART + 4 * tb) = st;
        else               *(float4*)(sm + OFF_PART + 336 + 4 * tb) = st;
      }
    }
    __syncthreads();
    if (tid < NB) {
      float* o = sm + OFF_OUTB + t0c + 4 * tid;
      const float* p = sm + OFF_PART + 4 * tid;
      const float* q = sm + OFF_PART + 336 + 4 * tid;
      #pragma unroll
      for (int j = 0; j < 4; ++j) o[j] = o[j] + p[j] + q[j];
    }
    __syncthreads();
  }

  // ---------------- epilogue: softplus, /amax, masked 1e4-softmax ----------------
  float lm = -INFINITY;
  for (int t = tid; t < LW; t += TPB) {
    float z = sm[OFF_OUTB + t];
    float sp = fmaxf(z, 0.f) + log1pf(expf(-fabsf(z)));   // stable softplus
    sm[OFF_OUTB + t] = sp;
    lm = fmaxf(lm, sp);
  }
  const float amax = blk_red_max(lm, red) + 1e-10f;
  const float* mrow = mask_g + (size_t)b * LW;
  float lm2 = -INFINITY;
  for (int t = tid; t < LW; t += TPB) {
    float v = 1e4f * (sm[OFF_OUTB + t] / amax) * mrow[t];
    sm[OFF_OUTB + t] = v;
    lm2 = fmaxf(lm2, v);
  }
  const float m2 = blk_red_max(lm2, red);
  float ls = 0.f;
  for (int t = tid; t < LW; t += TPB) {
    float e = expf(sm[OFF_OUTB + t] - m2);
    sm[OFF_OUTB + t] = e;
    ls += e;
  }
  const float S2 = blk_red_sum(ls, red);
  const float invs = 1.f / S2;
  float* orow = out_g + (size_t)b * LW;
  for (int t = tid; t < LW; t += TPB) orow[t] = sm[OFF_OUTB + t] * invs;
}

extern "C" void kernel_launch(void* const* d_in, const int* in_sizes, int n_in,
                              void* d_out, int out_size, void* d_ws, size_t ws_size,
                              hipStream_t stream) {
  (void)n_in; (void)d_ws; (void)ws_size; (void)out_size;
  const float* wf   = (const float*)d_in[0];
  const float* mask = (const float*)d_in[1];
  const float* spe  = (const float*)d_in[2];
  const float* wca  = (const float*)d_in[3];
  const float* wx   = (const float*)d_in[4];
  const float* wdv  = (const float*)d_in[5];
  const float* wrl  = (const float*)d_in[6];
  const float* wsub = (const float*)d_in[7];
  const float* wcb  = (const float*)d_in[8];
  const float* wp   = (const float*)d_in[9];
  const int B = in_sizes[0] / LW;
  hipLaunchKernelGGL(spot_kernel, dim3(B), dim3(TPB), 0, stream,
                     wf, mask, spe, wca, wx, wdv, wrl, wsub, wcb, wp, (float*)d_out);
}

// Round 3
// 338.190 us; speedup vs baseline: 3.0364x; 3.0364x over previous
//
#include <hip/hip_runtime.h>
#include <math.h>

#define TPB 256
#define LW  1000
#define CSTR 1124   // f1e per-channel stride (1000 + 2*60 halo + 4 pad)

// ---- LDS layout (float offsets) ----
#define OFF_WFE   0        // 1200  wf reflect-extended (halo 100)
#define OFF_CUME  1200     // 1200  cumsum reflect-extended
#define OFF_DSE   2400     // 1200  div_x_smd reflect-extended
#define OFF_F1E   3600     // 3372 = 3*1124 features1_norm, halo 60
#define OFF_D1    3600     // alias (1000): 9-tap derivative, dead before f1 written
#define OFF_SCAND 4600     // alias (512 floats = 256 doubles), dead before f1 written
#define OFF_OUTB  6972     // 1000 pre-softmax buffer
#define OFF_RED   7972     // 8 reduction scratch
#define SMEM_F    7980     // 31,920 bytes
// reuse of [0,3600) after wfe/cume/dse are dead:
#define OFF_KC    0        // 372 = 3*124 composed kernel
#define OFF_WS2   384      // 945 = 15*3*21 w_sub flat
#define OFF_F2V   1344     // 1500 = 15*100 phantom features2 at edges

__device__ __forceinline__ float4 ld4(const float* p) { return *(const float4*)p; }

__device__ __forceinline__ float blk_red_max(float v, float* red) {
  #pragma unroll
  for (int o = 32; o > 0; o >>= 1) v = fmaxf(v, __shfl_xor(v, o, 64));
  const int w = threadIdx.x >> 6;
  if ((threadIdx.x & 63) == 0) red[w] = v;
  __syncthreads();
  float r = fmaxf(fmaxf(red[0], red[1]), fmaxf(red[2], red[3]));
  __syncthreads();
  return r;
}

__device__ __forceinline__ float blk_red_sum(float v, float* red) {
  #pragma unroll
  for (int o = 32; o > 0; o >>= 1) v += __shfl_xor(v, o, 64);
  const int w = threadIdx.x >> 6;
  if ((threadIdx.x & 63) == 0) red[w] = v;
  __syncthreads();
  float r = red[0] + red[1] + red[2] + red[3];
  __syncthreads();
  return r;
}

__device__ __forceinline__ int refl(int j) {
  return j < 0 ? -j : (j >= LW ? 2 * LW - 2 - j : j);
}

// P[m][cin][k] = sum_q conv(wcb[q,:,m], wsub[3q+m][cin])[k], k in [0,121)
extern "C" __global__ void prep_kernel(const float* __restrict__ wsub_g,
                                       const float* __restrict__ wcb_g,
                                       float* __restrict__ P) {
  const int task = blockIdx.x * blockDim.x + threadIdx.x;
  if (task >= 1089) return;
  const int m = task / 363;
  const int r = task - m * 363;
  const int cin = r / 121;
  const int k = r - cin * 121;
  float acc = 0.f;
  for (int q = 0; q < 5; ++q) {
    const int ch = 3 * q + m;
    const float* ws = wsub_g + (ch * 3 + cin) * 21;
    #pragma unroll
    for (int j = 0; j < 21; ++j) {
      const int a = k - j;
      if (a >= 0 && a <= 100) acc = fmaf(ws[j], wcb_g[q * 303 + a * 3 + m], acc);
    }
  }
  P[task] = acc;
}

extern "C" __global__ void __launch_bounds__(TPB, 5)
spot_kernel(const float* __restrict__ wf_g,  const float* __restrict__ mask_g,
            const float* __restrict__ spe_g, const float* __restrict__ wca_g,
            const float* __restrict__ wx_g,  const float* __restrict__ wdv_g,
            const float* __restrict__ wrl_g, const float* __restrict__ wsub_g,
            const float* __restrict__ wcb_g, const float* __restrict__ wp_g,
            const float* __restrict__ P_g,   float* __restrict__ out_g)
{
  __shared__ __align__(16) float sm[SMEM_F];
  const int tid = threadIdx.x;
  const int b = blockIdx.x;
  const float* wf = wf_g + (size_t)b * LW;
  float* red = sm + OFF_RED;

  // ---------------- phase 0: staging, maxima, scan partials ----------------
  float hmx = -INFINITY;
  for (int i = tid; i < 1200; i += TPB) sm[OFF_WFE + i] = wf[refl(i - 100)];
  for (int t = tid; t < LW; t += TPB) hmx = fmaxf(hmx, wf[t]);
  float smx = -INFINITY;
  for (int t = tid; t < LW; t += TPB) smx = fmaxf(smx, spe_g[t]);
  double* scand = (double*)(sm + OFF_SCAND);
  double l0 = 0, l1 = 0, l2 = 0, l3 = 0;
  if (tid < 250) {
    l0 = (double)wf[4 * tid + 0];
    l1 = l0 + (double)wf[4 * tid + 1];
    l2 = l1 + (double)wf[4 * tid + 2];
    l3 = l2 + (double)wf[4 * tid + 3];
  }
  scand[tid] = l3;

  hmx = blk_red_max(hmx, red);   // barriers publish wfe/scand
  smx = blk_red_max(smx, red);

  // per-sample 3-way mixing weights W
  const float h = hmx / smx;
  float a0 = -fmaxf(h - wp_g[0], 0.f);
  float a1 = -fmaxf(h - wp_g[1], 0.f);
  float a2 = -fmaxf(h - wp_g[2], 0.f);
  float am = fmaxf(a0, fmaxf(a1, a2));
  float e0 = expf(a0 - am), e1 = expf(a1 - am), e2 = expf(a2 - am);
  float es = e0 + e1 + e2;
  float Wv[3] = { e0 / es, e1 / es, e2 / es };
  float swca = 0.f;
  for (int k = 0; k < 121; ++k) swca += wca_g[k];   // uniform scalar loads

  // ---------------- cumsum: fp64 block scan ----------------
  if (tid < 64) {
    double s0 = scand[4 * tid], s1 = scand[4 * tid + 1];
    double s2 = scand[4 * tid + 2], s3 = scand[4 * tid + 3];
    double tot = s0 + s1 + s2 + s3;
    double inc = tot;
    #pragma unroll
    for (int o = 1; o < 64; o <<= 1) {
      double n = __shfl_up(inc, o, 64);
      if ((tid & 63) >= o) inc += n;
    }
    double ex = inc - tot;
    scand[4 * tid]     = ex;
    scand[4 * tid + 1] = ex + s0;
    scand[4 * tid + 2] = ex + s0 + s1;
    scand[4 * tid + 3] = ex + s0 + s1 + s2;
  }
  __syncthreads();
  if (tid < 250) {
    double base = scand[tid];
    float4 cv = { (float)(base + l0), (float)(base + l1),
                  (float)(base + l2), (float)(base + l3) };
    *(float4*)(sm + OFF_CUME + 100 + 4 * tid) = cv;   // aligned, conflict-free
  }
  // d1: 9-tap derivative, zero padded (uses wfe core)
  const float dker[9] = {1.f/280.f, -4.f/105.f, 0.2f, -0.8f, 0.f, 0.8f, -0.2f, 4.f/105.f, -1.f/280.f};
  for (int t = tid; t < LW; t += TPB) {
    float a = 0.f;
    #pragma unroll
    for (int k = 0; k < 9; ++k) {
      if (k == 4) continue;
      int j = t + k - 4;
      float x = (j >= 0 && j < LW) ? sm[OFF_WFE + 100 + j] : 0.f;
      a = fmaf(dker[k], x, a);
    }
    sm[OFF_D1 + t] = a;
  }
  __syncthreads();
  // cum halos + dse core (51-tap running mean of d1, zero padded)
  for (int i = tid; i < 100; i += TPB) {
    sm[OFF_CUME + i]        = sm[OFF_CUME + 200 - i];
    sm[OFF_CUME + 1100 + i] = sm[OFF_CUME + 1098 - i];
  }
  for (int t = tid; t < LW; t += TPB) {
    int lo = t - 25 < 0 ? 0 : t - 25;
    int hi = t + 25 >= LW ? LW - 1 : t + 25;
    float a = 0.f;
    for (int j = lo; j <= hi; ++j) a += sm[OFF_D1 + j];
    sm[OFF_DSE + 100 + t] = a * (1.f / 51.f);
  }
  __syncthreads();
  for (int i = tid; i < 100; i += TPB) {
    sm[OFF_DSE + i]        = sm[OFF_DSE + 200 - i];
    sm[OFF_DSE + 1100 + i] = sm[OFF_DSE + 1098 - i];
  }
  __syncthreads();

  // ---------------- fused 121/101-tap reflect convs -> features1 ----------------
  float lsC = 0.f, lsX = 0.f, lsD = 0.f;
  if (tid < 250) {
    const int t0 = 4 * tid;
    const float* ce = sm + OFF_CUME + t0;
    const float* we = sm + OFF_WFE + t0;
    const float* de = sm + OFF_DSE + t0;
    float cw_[8], ww_[8], dw_[8];
    *(float4*)cw_ = ld4(ce); *(float4*)(cw_ + 4) = ld4(ce + 4);
    *(float4*)ww_ = ld4(we); *(float4*)(ww_ + 4) = ld4(we + 4);
    *(float4*)dw_ = ld4(de); *(float4*)(dw_ + 4) = ld4(de + 4);
    float aC[4] = {0,0,0,0}, aB[4] = {0,0,0,0}, aX[4] = {0,0,0,0}, aD[4] = {0,0,0,0};
    for (int g = 0; g < 120; g += 4) {
      #pragma unroll
      for (int kk = 0; kk < 4; ++kk) {
        const int k = g + kk;
        const float wa = wca_g[k], wxk = wx_g[k], wdk = wdv_g[k];
        #pragma unroll
        for (int j = 0; j < 4; ++j) {
          aC[j] = fmaf(wa,  cw_[kk + j], aC[j]);
          aX[j] = fmaf(wxk, ww_[kk + j], aX[j]);
          aD[j] = fmaf(wdk, dw_[kk + j], aD[j]);
        }
        if (k <= 100) {
          const float wr = wrl_g[k];
          #pragma unroll
          for (int j = 0; j < 4; ++j) aB[j] = fmaf(wr, cw_[kk + j], aB[j]);
        }
      }
      #pragma unroll
      for (int j = 0; j < 4; ++j) { cw_[j] = cw_[j+4]; ww_[j] = ww_[j+4]; dw_[j] = dw_[j+4]; }
      *(float4*)(cw_ + 4) = ld4(ce + g + 8);
      *(float4*)(ww_ + 4) = ld4(we + g + 8);
      *(float4*)(dw_ + 4) = ld4(de + g + 8);
    }
    { // tail tap k=120
      const float wa = wca_g[120], wxk = wx_g[120], wdk = wdv_g[120];
      #pragma unroll
      for (int j = 0; j < 4; ++j) {
        aC[j] = fmaf(wa,  cw_[j], aC[j]);
        aX[j] = fmaf(wxk, ww_[j], aX[j]);
        aD[j] = fmaf(wdk, dw_[j], aD[j]);
      }
    }
    float4 vC, vX, vD;
    float* pC = (float*)&vC; float* pX = (float*)&vX; float* pD = (float*)&vD;
    #pragma unroll
    for (int j = 0; j < 4; ++j) {
      float fc = fmaxf(fmaf(-aB[j], swca, aC[j]), 0.f);
      float fx = fmaxf(aX[j], 0.f);
      float fd = fmaxf(aD[j], 0.f);
      pC[j] = fc; pX[j] = fx; pD[j] = fd;
      lsC += fc; lsX += fx; lsD += fd;
    }
    *(float4*)(sm + OFF_F1E + 0 * CSTR + 60 + t0) = vC;
    *(float4*)(sm + OFF_F1E + 1 * CSTR + 60 + t0) = vX;
    *(float4*)(sm + OFF_F1E + 2 * CSTR + 60 + t0) = vD;
  }
  const float SC = blk_red_sum(lsC, red) + 1e-10f;   // barriers publish f1e
  const float SX = blk_red_sum(lsX, red) + 1e-10f;
  const float SD = blk_red_sum(lsD, red) + 1e-10f;
  {
    const float iC = 1.f / SC, iX = 1.f / SX, iD = 1.f / SD;
    for (int t = tid; t < LW; t += TPB) {
      sm[OFF_F1E + 0 * CSTR + 60 + t] *= iC;
      sm[OFF_F1E + 1 * CSTR + 60 + t] *= iX;
      sm[OFF_F1E + 2 * CSTR + 60 + t] *= iD;
    }
  }
  __syncthreads();

  // ---------------- halos(60) + Kc build + w_sub stage (wfe/cume/dse now dead) --
  for (int i = tid; i < 372; i += TPB) {
    const int c = i / 124, j = i - c * 124;
    const int dst = (j < 60) ? j : (1000 + j);          // right: 1060..1123
    const int src = (j < 60) ? (120 - j) : (1118 - j);  // 2118-(1000+j)
    sm[OFF_F1E + c * CSTR + dst] = sm[OFF_F1E + c * CSTR + src];
  }
  for (int i = tid; i < 363; i += TPB) {
    const int cin = i / 121, k = i - cin * 121;
    const float* Pp = P_g + cin * 121 + k;              // m-stride 363
    sm[OFF_KC + cin * 124 + k] =
        fmaf(Wv[0], Pp[0], fmaf(Wv[1], Pp[363], Wv[2] * Pp[726]));
  }
  for (int i = tid; i < 945; i += TPB) sm[OFF_WS2 + i] = wsub_g[i];
  __syncthreads();

  // ---------------- composed 3x121 conv -> outb; phantom f2 at edges ----------
  if (tid < 250) {
    const int t0 = 4 * tid;
    float acc[4] = {0,0,0,0};
    #pragma unroll
    for (int cin = 0; cin < 3; ++cin) {
      const float* xr = sm + OFF_F1E + cin * CSTR + t0;
      const float* kc = sm + OFF_KC + cin * 124;
      float xw[8];
      *(float4*)xw = ld4(xr); *(float4*)(xw + 4) = ld4(xr + 4);
      for (int g = 0; g < 120; g += 4) {
        #pragma unroll
        for (int kk = 0; kk < 4; ++kk) {
          const float w = kc[g + kk];                   // LDS broadcast
          #pragma unroll
          for (int j = 0; j < 4; ++j) acc[j] = fmaf(w, xw[kk + j], acc[j]);
        }
        #pragma unroll
        for (int j = 0; j < 4; ++j) xw[j] = xw[j + 4];
        *(float4*)(xw + 4) = ld4(xr + g + 8);
      }
      const float w120 = kc[120];
      #pragma unroll
      for (int j = 0; j < 4; ++j) acc[j] = fmaf(w120, xw[j], acc[j]);
    }
    float4 st = {acc[0], acc[1], acc[2], acc[3]};
    *(float4*)(sm + OFF_OUTB + t0) = st;
  }
  // phantom features2 at u in [-50,-1] and [1000,1050): f2v[ch][up]
  for (int task = tid; task < 1500; task += TPB) {
    const int ch = task / 100, up = task - ch * 100;
    const int u = (up < 50) ? (up - 50) : (950 + up);
    float acc2 = 0.f;
    #pragma unroll
    for (int cin = 0; cin < 3; ++cin) {
      const float* xr = sm + OFF_F1E + cin * CSTR + (50 + u);  // 60+u-10
      const float* wr = sm + OFF_WS2 + (ch * 3 + cin) * 21;
      #pragma unroll
      for (int j = 0; j < 21; ++j) acc2 = fmaf(wr[j], xr[j], acc2);
    }
    sm[OFF_F2V + ch * 100 + up] = acc2;
  }
  __syncthreads();

  // ---------------- edge corrections: subtract phantom contributions ----------
  if (tid < 100) {
    float corr = 0.f;
    if (tid < 50) {
      const int t = tid;
      for (int a = 0; a < 50; ++a) {
        if (t + a <= 49) {
          const int up = t + a;
          #pragma unroll
          for (int m = 0; m < 3; ++m) {
            const float wvm = Wv[m];
            #pragma unroll
            for (int q = 0; q < 5; ++q)
              corr = fmaf(wvm * wcb_g[q * 303 + a * 3 + m],
                          sm[OFF_F2V + (3 * q + m) * 100 + up], corr);
          }
        }
      }
      sm[OFF_OUTB + t] -= corr;
    } else {
      const int tp = tid;               // 50..99 -> t = 900+tp in [950,1000)
      const int t = 900 + tp;
      for (int d = 0; d < 50; ++d) {
        if (tp - d >= 50) {
          const int up = tp - d;
          const int a = 100 - d;
          #pragma unroll
          for (int m = 0; m < 3; ++m) {
            const float wvm = Wv[m];
            #pragma unroll
            for (int q = 0; q < 5; ++q)
              corr = fmaf(wvm * wcb_g[q * 303 + a * 3 + m],
                          sm[OFF_F2V + (3 * q + m) * 100 + up], corr);
          }
        }
      }
      sm[OFF_OUTB + t] -= corr;
    }
  }
  __syncthreads();

  // ---------------- epilogue: softplus, /amax, masked 1e4-softmax --------------
  float lm = -INFINITY;
  for (int t = tid; t < LW; t += TPB) {
    float z = sm[OFF_OUTB + t];
    float sp = fmaxf(z, 0.f) + log1pf(expf(-fabsf(z)));   // stable softplus
    sm[OFF_OUTB + t] = sp;
    lm = fmaxf(lm, sp);
  }
  const float amax = blk_red_max(lm, red) + 1e-10f;
  const float* mrow = mask_g + (size_t)b * LW;
  float lm2 = -INFINITY;
  for (int t = tid; t < LW; t += TPB) {
    float v = 1e4f * (sm[OFF_OUTB + t] / amax) * mrow[t];
    sm[OFF_OUTB + t] = v;
    lm2 = fmaxf(lm2, v);
  }
  const float m2 = blk_red_max(lm2, red);
  float ls = 0.f;
  for (int t = tid; t < LW; t += TPB) {
    float e = expf(sm[OFF_OUTB + t] - m2);
    sm[OFF_OUTB + t] = e;
    ls += e;
  }
  const float S2 = blk_red_sum(ls, red);
  const float invs = 1.f / S2;
  float* orow = out_g + (size_t)b * LW;
  for (int t = tid; t < LW; t += TPB) orow[t] = sm[OFF_OUTB + t] * invs;
}

extern "C" void kernel_launch(void* const* d_in, const int* in_sizes, int n_in,
                              void* d_out, int out_size, void* d_ws, size_t ws_size,
                              hipStream_t stream) {
  (void)n_in; (void)ws_size; (void)out_size;
  const float* wf   = (const float*)d_in[0];
  const float* mask = (const float*)d_in[1];
  const float* spe  = (const float*)d_in[2];
  const float* wca  = (const float*)d_in[3];
  const float* wx   = (const float*)d_in[4];
  const float* wdv  = (const float*)d_in[5];
  const float* wrl  = (const float*)d_in[6];
  const float* wsub = (const float*)d_in[7];
  const float* wcb  = (const float*)d_in[8];
  const float* wp   = (const float*)d_in[9];
  float* P = (float*)d_ws;                       // 1089 floats
  const int B = in_sizes[0] / LW;
  hipLaunchKernelGGL(prep_kernel, dim3(5), dim3(TPB), 0, stream, wsub, wcb, P);
  hipLaunchKernelGGL(spot_kernel, dim3(B), dim3(TPB), 0, stream,
                     wf, mask, spe, wca, wx, wdv, wrl, wsub, wcb, wp, P, (float*)d_out);
}

// Round 4
// 283.211 us; speedup vs baseline: 3.6258x; 1.1941x over previous
//
#include <hip/hip_runtime.h>
#include <math.h>

#define TPB 256
#define LW  1000
#define CSTR 1124   // f1e per-channel stride (1000 + 2*60 halo + 4 pad)

// ---- LDS layout (float offsets) ----
#define OFF_WFE   0        // 1120: wf reflect-ext, orig [-100,1020), core at +100
#define OFF_CUME  1120     // 1120: cumsum reflect-ext, core at +100
#define OFF_DSE   2240     // 1120: div_x_smd reflect-ext, core at +100
#define OFF_F1E   3360     // 3372 (+pad): features1_norm, core at +60, stride 1124
#define OFF_SCAND 3360     // alias: 512 floats = 256 doubles (wf fp64 scan)
#define OFF_C     3872     // alias: 1000 floats (d1 cumsum)
#define OFF_RED   6740     // 8 reduction scratch
#define SMEM_F    6748     // 26,992 B -> 6 blocks/CU
// phase-2 aliases of [0,3360) (staging dead after fused conv):
#define OFF_KC    0        // 372 composed kernel
#define OFF_WS2   376      // 1080 = 15*3 rows, stride 24 (21 used)
#define OFF_F2V   1456     // 1560 = 15*104: phantom f2; left at [0,50), right at [52,102)
#define OFF_PART  0        // 500 (alias KC/WS2 head; written after their last use)

__device__ __forceinline__ float4 ld4(const float* p) { return *(const float4*)p; }

__device__ __forceinline__ float blk_red_max(float v, float* red) {
  #pragma unroll
  for (int o = 32; o > 0; o >>= 1) v = fmaxf(v, __shfl_xor(v, o, 64));
  const int w = threadIdx.x >> 6;
  if ((threadIdx.x & 63) == 0) red[w] = v;
  __syncthreads();
  float r = fmaxf(fmaxf(red[0], red[1]), fmaxf(red[2], red[3]));
  __syncthreads();
  return r;
}

__device__ __forceinline__ float blk_red_sum(float v, float* red) {
  #pragma unroll
  for (int o = 32; o > 0; o >>= 1) v += __shfl_xor(v, o, 64);
  const int w = threadIdx.x >> 6;
  if ((threadIdx.x & 63) == 0) red[w] = v;
  __syncthreads();
  float r = red[0] + red[1] + red[2] + red[3];
  __syncthreads();
  return r;
}

__device__ __forceinline__ int refl(int j) {
  return j < 0 ? -j : (j >= LW ? 2 * LW - 2 - j : j);
}

// phantom-f2 inner: 21-tap conv, 4 outputs, sliding b128 window.
// OFF0 is the compile-time misalignment (0 for left side, 2 for right side).
template<int OFF0>
__device__ __forceinline__ void f2v_accum(const float* xr, const float* wr, float acc[4]) {
  float xw[12];
  *(float4*)xw       = ld4(xr);
  *(float4*)(xw + 4) = ld4(xr + 4);
  *(float4*)(xw + 8) = ld4(xr + 8);
  #pragma unroll
  for (int jb = 0; jb < 20; jb += 4) {
    float4 w4 = ld4(wr + jb);
    const float wv[4] = {w4.x, w4.y, w4.z, w4.w};
    #pragma unroll
    for (int kk = 0; kk < 4; ++kk)
      #pragma unroll
      for (int o = 0; o < 4; ++o)
        acc[o] = fmaf(wv[kk], xw[OFF0 + kk + o], acc[o]);
    #pragma unroll
    for (int j = 0; j < 8; ++j) xw[j] = xw[j + 4];
    *(float4*)(xw + 8) = ld4(xr + jb + 12);
  }
  const float w20 = wr[20];
  #pragma unroll
  for (int o = 0; o < 4; ++o) acc[o] = fmaf(w20, xw[OFF0 + o], acc[o]);
}

// P[m][cin][k] = sum_q conv(wcb[q,:,m], wsub[3q+m][cin])[k], k in [0,121)
// P[1089] = sum(wca); P[1090] = max(SPE)
extern "C" __global__ void prep_kernel(const float* __restrict__ wsub_g,
                                       const float* __restrict__ wcb_g,
                                       const float* __restrict__ wca_g,
                                       const float* __restrict__ spe_g,
                                       float* __restrict__ P) {
  __shared__ float sred[4];
  const int task = blockIdx.x * blockDim.x + threadIdx.x;
  if (task < 1089) {
    const int m = task / 363;
    const int r = task - m * 363;
    const int cin = r / 121;
    const int k = r - cin * 121;
    float acc = 0.f;
    for (int q = 0; q < 5; ++q) {
      const int ch = 3 * q + m;
      const float* ws = wsub_g + (ch * 3 + cin) * 21;
      #pragma unroll
      for (int j = 0; j < 21; ++j) {
        const int a = k - j;
        if (a >= 0 && a <= 100) acc = fmaf(ws[j], wcb_g[q * 303 + a * 3 + m], acc);
      }
    }
    P[task] = acc;
  } else if (task == 1089) {
    float s = 0.f;
    for (int k = 0; k < 121; ++k) s += wca_g[k];
    P[1089] = s;
  }
  if (blockIdx.x == 4) {   // SPE max
    float mx = -INFINITY;
    for (int t = threadIdx.x; t < LW; t += TPB) mx = fmaxf(mx, spe_g[t]);
    #pragma unroll
    for (int o = 32; o > 0; o >>= 1) mx = fmaxf(mx, __shfl_xor(mx, o, 64));
    if ((threadIdx.x & 63) == 0) sred[threadIdx.x >> 6] = mx;
    __syncthreads();
    if (threadIdx.x == 0)
      P[1090] = fmaxf(fmaxf(sred[0], sred[1]), fmaxf(sred[2], sred[3]));
  }
}

extern "C" __global__ void __launch_bounds__(TPB, 6)
spot_kernel(const float* __restrict__ wf_g,  const float* __restrict__ mask_g,
            const float* __restrict__ spe_g, const float* __restrict__ wca_g,
            const float* __restrict__ wx_g,  const float* __restrict__ wdv_g,
            const float* __restrict__ wrl_g, const float* __restrict__ wsub_g,
            const float* __restrict__ wcb_g, const float* __restrict__ wp_g,
            const float* __restrict__ P_g,   float* __restrict__ out_g)
{
  __shared__ __align__(16) float sm[SMEM_F];
  const int tid = threadIdx.x;
  const int b = blockIdx.x;
  const float* wf = wf_g + (size_t)b * LW;
  float* red = sm + OFF_RED;
  const int t0 = 4 * tid;

  // ---------------- phase 0: staging, maxima, wf fp64 scan partials ----------
  for (int i = tid; i < 1120; i += TPB) sm[OFF_WFE + i] = wf[refl(i - 100)];
  double* scand = (double*)(sm + OFF_SCAND);
  double l0 = 0, l1 = 0, l2 = 0, l3 = 0;
  float hmx = -INFINITY;
  if (tid < 250) {
    float4 wv4 = ld4(wf + t0);
    hmx = fmaxf(fmaxf(wv4.x, wv4.y), fmaxf(wv4.z, wv4.w));
    l0 = (double)wv4.x;
    l1 = l0 + (double)wv4.y;
    l2 = l1 + (double)wv4.z;
    l3 = l2 + (double)wv4.w;
  }
  scand[tid] = l3;
  hmx = blk_red_max(hmx, red);   // barriers publish wfe/scand

  // per-sample 3-way mixing weights W
  const float smx = P_g[1090];
  const float swca = P_g[1089];
  const float h = hmx / smx;
  float a0 = -fmaxf(h - wp_g[0], 0.f);
  float a1 = -fmaxf(h - wp_g[1], 0.f);
  float a2 = -fmaxf(h - wp_g[2], 0.f);
  float am = fmaxf(a0, fmaxf(a1, a2));
  float e0 = expf(a0 - am), e1 = expf(a1 - am), e2 = expf(a2 - am);
  float es = e0 + e1 + e2;
  float Wv[3] = { e0 / es, e1 / es, e2 / es };

  // ---------------- wf cumsum: fp64 block scan ----------------
  if (tid < 64) {
    double s0 = scand[4 * tid], s1 = scand[4 * tid + 1];
    double s2 = scand[4 * tid + 2], s3 = scand[4 * tid + 3];
    double tot = s0 + s1 + s2 + s3;
    double inc = tot;
    #pragma unroll
    for (int o = 1; o < 64; o <<= 1) {
      double n = __shfl_up(inc, o, 64);
      if ((tid & 63) >= o) inc += n;
    }
    double ex = inc - tot;
    scand[4 * tid]     = ex;
    scand[4 * tid + 1] = ex + s0;
    scand[4 * tid + 2] = ex + s0 + s1;
    scand[4 * tid + 3] = ex + s0 + s1 + s2;
  }
  __syncthreads();                                   // B1
  if (tid < 250) {
    double base = scand[tid];
    float4 cv = { (float)(base + l0), (float)(base + l1),
                  (float)(base + l2), (float)(base + l3) };
    *(float4*)(sm + OFF_CUME + 100 + t0) = cv;
  }
  // d1 (9-tap derivative, zero-padded) in registers + fp32 scan partials
  const float dker[9] = {1.f/280.f, -4.f/105.f, 0.2f, -0.8f, 0.f, 0.8f, -0.2f, 4.f/105.f, -1.f/280.f};
  float dv0 = 0, dv1 = 0, dv2 = 0, dv3 = 0;
  if (tid >= 1 && tid <= 248) {          // safe interior: orig window [t0-4, t0+7]
    float xw[12];
    const float* xr = sm + OFF_WFE + t0 + 96;
    *(float4*)xw = ld4(xr); *(float4*)(xw+4) = ld4(xr+4); *(float4*)(xw+8) = ld4(xr+8);
    float d[4];
    #pragma unroll
    for (int j = 0; j < 4; ++j) {
      float a = 0.f;
      #pragma unroll
      for (int k = 0; k < 9; ++k) {
        if (k == 4) continue;
        a = fmaf(dker[k], xw[j + k], a);
      }
      d[j] = a;
    }
    dv0 = d[0]; dv1 = d[1]; dv2 = d[2]; dv3 = d[3];
  } else if (tid == 0 || tid == 249) {   // edges: zero-padded scalar path
    float d[4];
    #pragma unroll
    for (int j = 0; j < 4; ++j) {
      float a = 0.f;
      for (int k = 0; k < 9; ++k) {
        if (k == 4) continue;
        const int o = t0 + j - 4 + k;
        if (o >= 0 && o < LW) a = fmaf(dker[k], sm[OFF_WFE + 100 + o], a);
      }
      d[j] = a;
    }
    dv0 = d[0]; dv1 = d[1]; dv2 = d[2]; dv3 = d[3];
  }
  // fp32 scan of d1
  {
    const float s0 = dv0, s1 = s0 + dv1, s2 = s1 + dv2, s3 = s2 + dv3;
    float inc = s3;
    const int lane = tid & 63;
    #pragma unroll
    for (int o = 1; o < 64; o <<= 1) {
      float n = __shfl_up(inc, o, 64);
      if (lane >= o) inc += n;
    }
    float* redw = red + 4;
    if (lane == 63) redw[tid >> 6] = inc;
    __syncthreads();                                 // B2 (publishes CUME core too)
    float base = 0.f;
    for (int w = 0; w < (tid >> 6); ++w) base += redw[w];
    if (tid < 250) {
      const float ex = base + inc - s3;
      float4 cv = { ex + s0, ex + s1, ex + s2, ex + s3 };
      *(float4*)(sm + OFF_C + t0) = cv;
    }
  }
  __syncthreads();                                   // B3
  // dse core = (C[t+25]-C[t-26])/51 ; cume halos
  for (int t = tid; t < LW; t += TPB) {
    const float hi = sm[OFF_C + (t + 25 > 999 ? 999 : t + 25)];
    const float lo = (t >= 26) ? sm[OFF_C + t - 26] : 0.f;
    sm[OFF_DSE + 100 + t] = (hi - lo) * (1.f / 51.f);
  }
  for (int i = tid; i < 120; i += TPB) {
    if (i < 100) sm[OFF_CUME + i] = sm[OFF_CUME + 200 - i];
    else         sm[OFF_CUME + 1000 + i] = sm[OFF_CUME + 2198 - (1000 + i)];
  }
  __syncthreads();                                   // B4
  for (int i = tid; i < 120; i += TPB) {
    if (i < 100) sm[OFF_DSE + i] = sm[OFF_DSE + 200 - i];
    else         sm[OFF_DSE + 1000 + i] = sm[OFF_DSE + 2198 - (1000 + i)];
  }
  __syncthreads();                                   // B5

  // ---------------- fused 121/101-tap reflect convs -> features1 ------------
  float lsC = 0.f, lsX = 0.f, lsD = 0.f;
  if (tid < 250) {
    const float* ce = sm + OFF_CUME + t0;
    const float* we = sm + OFF_WFE + t0;
    const float* de = sm + OFF_DSE + t0;
    float cw_[8], ww_[8], dw_[8];
    *(float4*)cw_ = ld4(ce); *(float4*)(cw_ + 4) = ld4(ce + 4);
    *(float4*)ww_ = ld4(we); *(float4*)(ww_ + 4) = ld4(we + 4);
    *(float4*)dw_ = ld4(de); *(float4*)(dw_ + 4) = ld4(de + 4);
    float aC[4] = {0,0,0,0}, aB[4] = {0,0,0,0}, aX[4] = {0,0,0,0}, aD[4] = {0,0,0,0};
    for (int g = 0; g < 100; g += 4) {               // taps 0..99, all four convs
      #pragma unroll
      for (int kk = 0; kk < 4; ++kk) {
        const int k = g + kk;
        const float wa = wca_g[k], wxk = wx_g[k], wdk = wdv_g[k], wr = wrl_g[k];
        #pragma unroll
        for (int j = 0; j < 4; ++j) {
          aC[j] = fmaf(wa,  cw_[kk + j], aC[j]);
          aB[j] = fmaf(wr,  cw_[kk + j], aB[j]);
          aX[j] = fmaf(wxk, ww_[kk + j], aX[j]);
          aD[j] = fmaf(wdk, dw_[kk + j], aD[j]);
        }
      }
      #pragma unroll
      for (int j = 0; j < 4; ++j) { cw_[j] = cw_[j+4]; ww_[j] = ww_[j+4]; dw_[j] = dw_[j+4]; }
      *(float4*)(cw_ + 4) = ld4(ce + g + 8);
      *(float4*)(ww_ + 4) = ld4(we + g + 8);
      *(float4*)(dw_ + 4) = ld4(de + g + 8);
    }
    { // aB tap k=100 (window base = t0+100)
      const float wr100 = wrl_g[100];
      #pragma unroll
      for (int j = 0; j < 4; ++j) aB[j] = fmaf(wr100, cw_[j], aB[j]);
    }
    for (int g = 100; g < 116; g += 4) {             // taps 100..115, three convs
      #pragma unroll
      for (int kk = 0; kk < 4; ++kk) {
        const int k = g + kk;
        const float wa = wca_g[k], wxk = wx_g[k], wdk = wdv_g[k];
        #pragma unroll
        for (int j = 0; j < 4; ++j) {
          aC[j] = fmaf(wa,  cw_[kk + j], aC[j]);
          aX[j] = fmaf(wxk, ww_[kk + j], aX[j]);
          aD[j] = fmaf(wdk, dw_[kk + j], aD[j]);
        }
      }
      #pragma unroll
      for (int j = 0; j < 4; ++j) { cw_[j] = cw_[j+4]; ww_[j] = ww_[j+4]; dw_[j] = dw_[j+4]; }
      *(float4*)(cw_ + 4) = ld4(ce + g + 8);
      *(float4*)(ww_ + 4) = ld4(we + g + 8);
      *(float4*)(dw_ + 4) = ld4(de + g + 8);
    }
    #pragma unroll
    for (int kk = 0; kk < 5; ++kk) {                 // taps 116..120 from window
      const int k = 116 + kk;
      const float wa = wca_g[k], wxk = wx_g[k], wdk = wdv_g[k];
      #pragma unroll
      for (int j = 0; j < 4; ++j) {
        aC[j] = fmaf(wa,  cw_[kk + j], aC[j]);
        aX[j] = fmaf(wxk, ww_[kk + j], aX[j]);
        aD[j] = fmaf(wdk, dw_[kk + j], aD[j]);
      }
    }
    float4 vC, vX, vD;
    float* pC = (float*)&vC; float* pX = (float*)&vX; float* pD = (float*)&vD;
    #pragma unroll
    for (int j = 0; j < 4; ++j) {
      float fc = fmaxf(fmaf(-aB[j], swca, aC[j]), 0.f);
      float fx = fmaxf(aX[j], 0.f);
      float fd = fmaxf(aD[j], 0.f);
      pC[j] = fc; pX[j] = fx; pD[j] = fd;
      lsC += fc; lsX += fx; lsD += fd;
    }
    *(float4*)(sm + OFF_F1E + 0 * CSTR + 60 + t0) = vC;
    *(float4*)(sm + OFF_F1E + 1 * CSTR + 60 + t0) = vX;
    *(float4*)(sm + OFF_F1E + 2 * CSTR + 60 + t0) = vD;
  }
  const float SC = blk_red_sum(lsC, red) + 1e-10f;   // barriers publish f1
  const float SX = blk_red_sum(lsX, red) + 1e-10f;
  const float SD = blk_red_sum(lsD, red) + 1e-10f;
  {
    const float iC = 1.f / SC, iX = 1.f / SX, iD = 1.f / SD;
    for (int t = tid; t < LW; t += TPB) {
      sm[OFF_F1E + 0 * CSTR + 60 + t] *= iC;
      sm[OFF_F1E + 1 * CSTR + 60 + t] *= iX;
      sm[OFF_F1E + 2 * CSTR + 60 + t] *= iD;
    }
  }
  __syncthreads();                                   // B6

  // ---------------- f1 halos(60) + Kc + w_sub stage (staging dead) ----------
  for (int i = tid; i < 360; i += TPB) {
    const int c = i / 120, j = i - c * 120;
    const int dst = (j < 60) ? j : (1000 + j);          // right: 1060..1119
    const int src = (j < 60) ? (120 - j) : (1118 - j);
    sm[OFF_F1E + c * CSTR + dst] = sm[OFF_F1E + c * CSTR + src];
  }
  for (int i = tid; i < 363; i += TPB) {
    const int cin = i / 121, k = i - cin * 121;
    const float* Pp = P_g + cin * 121 + k;
    sm[OFF_KC + cin * 124 + k] =
        fmaf(Wv[0], Pp[0], fmaf(Wv[1], Pp[363], Wv[2] * Pp[726]));
  }
  for (int i = tid; i < 1080; i += TPB) {
    const int row = i / 24, k = i - row * 24;
    sm[OFF_WS2 + i] = (k < 21) ? wsub_g[row * 21 + k] : 0.f;
  }
  __syncthreads();                                   // B7

  // ---------------- composed 3x121 conv (regs) + vectorized phantom f2 ------
  float res[4] = {0, 0, 0, 0};
  if (tid < 250) {
    #pragma unroll
    for (int cin = 0; cin < 3; ++cin) {
      const float* xr = sm + OFF_F1E + cin * CSTR + t0;
      const float* kc = sm + OFF_KC + cin * 124;
      float xw[8];
      *(float4*)xw = ld4(xr); *(float4*)(xw + 4) = ld4(xr + 4);
      for (int g = 0; g < 120; g += 4) {
        float4 kw = ld4(kc + g);                     // LDS broadcast b128
        const float wv[4] = {kw.x, kw.y, kw.z, kw.w};
        #pragma unroll
        for (int kk = 0; kk < 4; ++kk)
          #pragma unroll
          for (int j = 0; j < 4; ++j) res[j] = fmaf(wv[kk], xw[kk + j], res[j]);
        #pragma unroll
        for (int j = 0; j < 4; ++j) xw[j] = xw[j + 4];
        *(float4*)(xw + 4) = ld4(xr + g + 8);
      }
      const float w120 = kc[120];
      #pragma unroll
      for (int j = 0; j < 4; ++j) res[j] = fmaf(w120, xw[j], res[j]);
    }
  }
  // phantom f2: 390 tasks (left 195, right 195), 4 outputs each
  for (int task = tid; task < 390; task += TPB) {
    const int side = (task >= 195) ? 1 : 0;
    const int r = task - 195 * side;
    const int ch = r / 13;
    const int gl = r - 13 * ch;
    float acc[4] = {0, 0, 0, 0};
    const float* wrb = sm + OFF_WS2 + ch * 72;
    if (side == 0) {
      const int xb = 4 * gl;
      #pragma unroll
      for (int cin = 0; cin < 3; ++cin)
        f2v_accum<0>(sm + OFF_F1E + cin * CSTR + xb, wrb + cin * 24, acc);
    } else {
      const int xb = 1048 + 4 * gl;
      #pragma unroll
      for (int cin = 0; cin < 3; ++cin)
        f2v_accum<2>(sm + OFF_F1E + cin * CSTR + xb, wrb + cin * 24, acc);
    }
    const int dst = OFF_F2V + ch * 104 + side * 52 + 4 * gl;
    if (gl < 12) {
      float4 st = {acc[0], acc[1], acc[2], acc[3]};
      *(float4*)(sm + dst) = st;
    } else {
      sm[dst] = acc[0]; sm[dst + 1] = acc[1];
    }
  }
  __syncthreads();                                   // B8

  // ---------------- edge-correction partials: 500 (q,tcol) tasks ------------
  for (int task = tid; task < 500; task += TPB) {
    const int q = task / 100;
    const int tcol = task - q * 100;
    const float* f0 = sm + OFF_F2V + (3 * q) * 104;
    float acc = 0.f;
    if (tcol < 50) {
      const int t = tcol;
      for (int a = 0; a <= 49 - t; ++a) {
        const int up = t + a;
        const float* wb = wcb_g + q * 303 + a * 3;
        acc = fmaf(Wv[0] * wb[0], f0[up], acc);
        acc = fmaf(Wv[1] * wb[1], f0[104 + up], acc);
        acc = fmaf(Wv[2] * wb[2], f0[208 + up], acc);
      }
    } else {
      const int tp = tcol;                           // t = 900+tp
      for (int d = 0; d <= tp - 50; ++d) {
        const int up = tp - d + 2;                   // +2: right-side layout shift
        const int a = 100 - d;
        const float* wb = wcb_g + q * 303 + a * 3;
        acc = fmaf(Wv[0] * wb[0], f0[up], acc);
        acc = fmaf(Wv[1] * wb[1], f0[104 + up], acc);
        acc = fmaf(Wv[2] * wb[2], f0[208 + up], acc);
      }
    }
    sm[OFF_PART + task] = acc;                       // PART[q*100+tcol]
  }
  __syncthreads();                                   // B9

  // ---------------- apply corrections + register-resident epilogue ----------
  if (tid < 250 && (t0 < 52 || t0 >= 948)) {
    #pragma unroll
    for (int j = 0; j < 4; ++j) {
      const int t = t0 + j;
      if (t < 50) {
        float c = 0.f;
        #pragma unroll
        for (int q = 0; q < 5; ++q) c += sm[OFF_PART + q * 100 + t];
        res[j] -= c;
      } else if (t >= 950) {
        const int tc = t - 900;
        float c = 0.f;
        #pragma unroll
        for (int q = 0; q < 5; ++q) c += sm[OFF_PART + q * 100 + tc];
        res[j] -= c;
      }
    }
  }
  float sp[4];
  float lm = -INFINITY;
  if (tid < 250) {
    #pragma unroll
    for (int j = 0; j < 4; ++j) {
      const float z = res[j];
      sp[j] = fmaxf(z, 0.f) + log1pf(expf(-fabsf(z)));   // stable softplus
      lm = fmaxf(lm, sp[j]);
    }
  }
  const float amax = blk_red_max(lm, red) + 1e-10f;
  float v4[4];
  float lm2 = -INFINITY;
  if (tid < 250) {
    const float4 mv = ld4(mask_g + (size_t)b * LW + t0);
    const float* mj = (const float*)&mv;
    const float ia = 1e4f / amax;
    #pragma unroll
    for (int j = 0; j < 4; ++j) {
      v4[j] = (sp[j] * ia) * mj[j];
      lm2 = fmaxf(lm2, v4[j]);
    }
  }
  const float m2 = blk_red_max(lm2, red);
  float ls = 0.f;
  float e4[4];
  if (tid < 250) {
    #pragma unroll
    for (int j = 0; j < 4; ++j) {
      e4[j] = expf(v4[j] - m2);
      ls += e4[j];
    }
  }
  const float S2 = blk_red_sum(ls, red);
  if (tid < 250) {
    const float invs = 1.f / S2;
    float4 st = { e4[0] * invs, e4[1] * invs, e4[2] * invs, e4[3] * invs };
    *(float4*)(out_g + (size_t)b * LW + t0) = st;
  }
}

extern "C" void kernel_launch(void* const* d_in, const int* in_sizes, int n_in,
                              void* d_out, int out_size, void* d_ws, size_t ws_size,
                              hipStream_t stream) {
  (void)n_in; (void)ws_size; (void)out_size;
  const float* wf   = (const float*)d_in[0];
  const float* mask = (const float*)d_in[1];
  const float* spe  = (const float*)d_in[2];
  const float* wca  = (const float*)d_in[3];
  const float* wx   = (const float*)d_in[4];
  const float* wdv  = (const float*)d_in[5];
  const float* wrl  = (const float*)d_in[6];
  const float* wsub = (const float*)d_in[7];
  const float* wcb  = (const float*)d_in[8];
  const float* wp   = (const float*)d_in[9];
  float* P = (float*)d_ws;                       // 1091 floats
  const int B = in_sizes[0] / LW;
  hipLaunchKernelGGL(prep_kernel, dim3(5), dim3(TPB), 0, stream, wsub, wcb, wca, spe, P);
  hipLaunchKernelGGL(spot_kernel, dim3(B), dim3(TPB), 0, stream,
                     wf, mask, spe, wca, wx, wdv, wrl, wsub, wcb, wp, P, (float*)d_out);
}